// Round 3
// baseline (399.559 us; speedup 1.0000x reference)
//
#include <hip/hip_runtime.h>
#include <hip/hip_bf16.h>

#define NB 4
#define CI 128
#define CO 128
#define HH 128
#define WW 128
#define HW 16384
#define KK 9

typedef __attribute__((ext_vector_type(4))) float f32x4;
typedef __attribute__((ext_vector_type(4))) unsigned int u32x4;
typedef __attribute__((ext_vector_type(8))) short bf16x8;

static __device__ __forceinline__ unsigned short f2bf(float v) {
  __hip_bfloat16 h = __float2bfloat16(v);
  return *reinterpret_cast<const unsigned short*>(&h);
}
static __device__ __forceinline__ unsigned int pk2(float lo, float hi) {
  return (unsigned int)f2bf(lo) | ((unsigned int)f2bf(hi) << 16);
}
static __device__ __forceinline__ float bflo(unsigned int u) {
  return __uint_as_float(u << 16);
}
static __device__ __forceinline__ float bfhi(unsigned int u) {
  return __uint_as_float(u & 0xFFFF0000u);
}

// ---------------- k_xpose: x NCHW f32 -> xT NHWC bf16 ----------------
__global__ __launch_bounds__(256) void k_xpose(const float* __restrict__ x,
                                               unsigned short* __restrict__ xT) {
  __shared__ float tile[128][65];
  const int bid = blockIdx.x;  // 4b x 128h x 2wc = 1024
  const int b = bid >> 8;
  const int h = (bid >> 1) & 127;
  const int w0 = (bid & 1) * 64;
  const int t = threadIdx.x;
  const int lw = t & 63;
  const float* xp = x + (size_t)b * CI * HW + h * WW + w0;
#pragma unroll
  for (int k = 0; k < 32; ++k) {
    int ci = (t >> 6) * 32 + k;
    tile[ci][lw] = xp[(size_t)ci * HW + lw];
  }
  __syncthreads();
  unsigned short* op = xT + ((size_t)(b * 128 + h) * 128 + w0) * 128;
  const int ci2 = (t & 63) * 2;
  const int wg = t >> 6;
#pragma unroll
  for (int k = 0; k < 16; ++k) {
    int w = wg * 16 + k;
    unsigned int p = (unsigned int)f2bf(tile[ci2][w]) | ((unsigned int)f2bf(tile[ci2 + 1][w]) << 16);
    *(unsigned int*)(op + (size_t)w * 128 + ci2) = p;
  }
}

// ---------------- k_wprep: w_dcn f32 -> bf16, layout [tap][co][ci] ----------------
__global__ __launch_bounds__(256) void k_wprep(const float* __restrict__ w,
                                               unsigned short* __restrict__ wT) {
  int i = blockIdx.x * 256 + threadIdx.x;
  if (i >= CO * CI * KK) return;
  int k = i % KK;
  int ci = (i / KK) & 127;
  int co = i / (KK * CI);
  wT[((size_t)k * CO + co) * CI + ci] = f2bf(w[i]);
}

// ---------------- k_wprep2: w_off f32 -> bf16, layout [tap][oc32][ci], oc>=18 zero ----------------
__global__ __launch_bounds__(256) void k_wprep2(const float* __restrict__ w,
                                                unsigned short* __restrict__ wT2) {
  int i = blockIdx.x * 256 + threadIdx.x;  // 9*32*128 = 36864
  if (i >= 9 * 32 * 128) return;
  int ci = i & 127;
  int oc = (i >> 7) & 31;
  int tap = i >> 12;
  unsigned short v = 0;
  if (oc < 18) v = f2bf(w[((size_t)(oc * 128 + ci)) * 9 + tap]);
  wT2[i] = v;
}

// ---------------- k_main: fused offset-conv + deformable sampling + GEMM + BN stats ----------------
// Block = 64 px (4h x 16w). Wave wv owns row h0+wv, all 128 co.
// Lane: colc = w-offset (A row), kg = ci-chunk. No __syncthreads until epilogue.
__global__ __launch_bounds__(256, 3) void k_main(
    const unsigned short* __restrict__ xT, const unsigned short* __restrict__ wT,
    const unsigned short* __restrict__ wT2, const float* __restrict__ b_off,
    float* __restrict__ outp, float* __restrict__ stats) {
  __shared__ float off_lds[4][32][16];  // 8 KB: [wave][oc][px_w]; reused for stats reduce

  const int bid0 = blockIdx.x;
  const int bid = (bid0 & 7) * 128 + (bid0 >> 3);  // XCD swizzle (1024 = 8*128, bijective)
  const int b = bid >> 8;
  const int rem = bid & 255;
  const int h0 = (rem >> 3) * 4;
  const int w0 = (rem & 7) * 16;
  const int t = threadIdx.x;
  const int l = t & 63;
  const int wv = t >> 6;
  const int colc = l & 15;
  const int kg = l >> 4;
  const int h = h0 + wv;
  const int wpx = w0 + colc;

  const unsigned short* xb = xT + (size_t)b * HW * 128;

  // ---- fused offset conv: wave's 16 px, 32 oc (18 valid), K = 9x128 ----
  f32x4 oacc[2];
  oacc[0] = (f32x4){0.f, 0.f, 0.f, 0.f};
  oacc[1] = (f32x4){0.f, 0.f, 0.f, 0.f};
#pragma unroll 1
  for (int tap = 0; tap < KK; ++tap) {
    int ty = tap / 3, tx = tap % 3;
    int yy = h - 1 + ty;
    int xx = wpx - 1 + tx;
    bool vld = ((unsigned)yy < 128u) && ((unsigned)xx < 128u);
    int yc = min(max(yy, 0), 127), xc = min(max(xx, 0), 127);
    const unsigned short* p = xb + ((size_t)(yc * 128 + xc)) * 128 + kg * 8;
#pragma unroll
    for (int ks = 0; ks < 4; ++ks) {
      u32x4 raw = *(const u32x4*)(p + ks * 32);
      if (!vld) raw = (u32x4){0u, 0u, 0u, 0u};
      bf16x8 afr = __builtin_bit_cast(bf16x8, raw);
#pragma unroll
      for (int nf = 0; nf < 2; ++nf) {
        bf16x8 bfr = *(const bf16x8*)(wT2 + ((size_t)(tap * 32 + nf * 16 + colc)) * 128 + ks * 32 + kg * 8);
        oacc[nf] = __builtin_amdgcn_mfma_f32_16x16x32_bf16(afr, bfr, oacc[nf], 0, 0, 0);
      }
    }
  }
  // D: oc = nf*16 + colc, px_w = kg*4 + r. Wave-private LDS transpose (no barrier needed).
#pragma unroll
  for (int nf = 0; nf < 2; ++nf) {
    int oc = nf * 16 + colc;
    float bo = (oc < 18) ? b_off[oc] : 0.f;
#pragma unroll
    for (int r = 0; r < 4; ++r) off_lds[wv][oc][kg * 4 + r] = oacc[nf][r] + bo;
  }

  // ---- main loop: sample + GEMM, all 128 co ----
  f32x4 acc[8];
#pragma unroll
  for (int nf = 0; nf < 8; ++nf) acc[nf] = (f32x4){0.f, 0.f, 0.f, 0.f};

#pragma unroll 1
  for (int tap = 0; tap < KK; ++tap) {
    int ty = tap / 3, tx = tap % 3;
    float dy = off_lds[wv][2 * tap][colc];
    float dx = off_lds[wv][2 * tap + 1][colc];
    float ys = (float)(h - 1 + ty) + dy;
    float xs = (float)(wpx - 1 + tx) + dx;
    float y0f = floorf(ys), x0f = floorf(xs);
    float fy = ys - y0f, fx = xs - x0f;
    int iy0 = (int)y0f, ix0 = (int)x0f;
    bool vy0 = (unsigned)iy0 < 128u, vy1 = (unsigned)(iy0 + 1) < 128u;
    bool vx0 = (unsigned)ix0 < 128u, vx1 = (unsigned)(ix0 + 1) < 128u;
    float fy0 = 1.f - fy, fx0 = 1.f - fx;
    float w00 = fy0 * fx0 * ((vy0 && vx0) ? 1.f : 0.f);
    float w01 = fy0 * fx * ((vy0 && vx1) ? 1.f : 0.f);
    float w10 = fy * fx0 * ((vy1 && vx0) ? 1.f : 0.f);
    float w11 = fy * fx * ((vy1 && vx1) ? 1.f : 0.f);
    int y0c = min(max(iy0, 0), 127), y1c = min(max(iy0 + 1, 0), 127);
    int x0c = min(max(ix0, 0), 127), x1c = min(max(ix0 + 1, 0), 127);
    const unsigned short* p00 = xb + ((size_t)(y0c * 128 + x0c)) * 128 + kg * 8;
    const unsigned short* p01 = xb + ((size_t)(y0c * 128 + x1c)) * 128 + kg * 8;
    const unsigned short* p10 = xb + ((size_t)(y1c * 128 + x0c)) * 128 + kg * 8;
    const unsigned short* p11 = xb + ((size_t)(y1c * 128 + x1c)) * 128 + kg * 8;
#pragma unroll
    for (int ks = 0; ks < 4; ++ks) {
      u32x4 r00 = *(const u32x4*)(p00 + ks * 32);
      u32x4 r01 = *(const u32x4*)(p01 + ks * 32);
      u32x4 r10 = *(const u32x4*)(p10 + ks * 32);
      u32x4 r11 = *(const u32x4*)(p11 + ks * 32);
      u32x4 pkv;
#pragma unroll
      for (int j = 0; j < 4; ++j) {
        float vlo = w00 * bflo(r00[j]) + w01 * bflo(r01[j]) + w10 * bflo(r10[j]) + w11 * bflo(r11[j]);
        float vhi = w00 * bfhi(r00[j]) + w01 * bfhi(r01[j]) + w10 * bfhi(r10[j]) + w11 * bfhi(r11[j]);
        pkv[j] = pk2(vlo, vhi);
      }
      bf16x8 afr = __builtin_bit_cast(bf16x8, pkv);
#pragma unroll
      for (int nf = 0; nf < 8; ++nf) {
        bf16x8 bfr = *(const bf16x8*)(wT + ((size_t)(tap * CO + nf * 16 + colc)) * CI + ks * 32 + kg * 8);
        acc[nf] = __builtin_amdgcn_mfma_f32_16x16x32_bf16(afr, bfr, acc[nf], 0, 0, 0);
      }
    }
  }

  // ---- epilogue: store pre-BN out + block-reduced BN stats ----
  const size_t ob = (size_t)b * CO * HW;
#pragma unroll
  for (int nf = 0; nf < 8; ++nf) {
    int co = nf * 16 + colc;
    *(f32x4*)&outp[ob + (size_t)co * HW + h * WW + w0 + kg * 4] = acc[nf];
  }
  // per-wave partials into wave-private LDS region (off_lds[wv] done being read by this wave)
  float* myred = &off_lds[wv][0][0];  // 512 floats per wave
#pragma unroll
  for (int nf = 0; nf < 8; ++nf) {
    float s = acc[nf][0] + acc[nf][1] + acc[nf][2] + acc[nf][3];
    float sq = acc[nf][0] * acc[nf][0] + acc[nf][1] * acc[nf][1] + acc[nf][2] * acc[nf][2] +
               acc[nf][3] * acc[nf][3];
    s += __shfl_xor(s, 16);
    s += __shfl_xor(s, 32);
    sq += __shfl_xor(sq, 16);
    sq += __shfl_xor(sq, 32);
    if (kg == 0) {
      int co = nf * 16 + colc;
      myred[co] = s;
      myred[128 + co] = sq;
    }
  }
  __syncthreads();
  const float* red = &off_lds[0][0][0];
  if (t < 128) {
    float s = red[t] + red[512 + t] + red[1024 + t] + red[1536 + t];
    atomicAdd(&stats[t], s);
  } else if (t < 256) {
    int c = t - 128;
    float q = red[128 + c] + red[512 + 128 + c] + red[1024 + 128 + c] + red[1536 + 128 + c];
    atomicAdd(&stats[CO + c], q);
  }
}

// ---------------- k_stats: fold stats -> per-channel scale/shift ----------------
__global__ void k_stats(const float* __restrict__ stats, const float* __restrict__ gamma,
                        const float* __restrict__ beta, float* __restrict__ sc) {
  int co = threadIdx.x;
  const float inv = 1.f / 65536.f;
  float mean = stats[co] * inv;
  float var = stats[CO + co] * inv - mean * mean;
  float scale = rsqrtf(var + 1e-3f) * gamma[co];
  sc[co] = scale;
  sc[CO + co] = beta[co] - mean * scale;
}

// ---------------- k_bn: in-place BN apply + ReLU (float4) ----------------
__global__ __launch_bounds__(256) void k_bn(float* __restrict__ outp,
                                            const float* __restrict__ sc) {
  int i = blockIdx.x * 256 + threadIdx.x;  // f32x4 index, 2097152 total
  f32x4 v = ((const f32x4*)outp)[i];
  int co = (i >> 12) & 127;
  float scale = sc[co], shift = sc[CO + co];
#pragma unroll
  for (int j = 0; j < 4; ++j) {
    float y = v[j] * scale + shift;
    v[j] = y > 0.f ? y : 0.f;
  }
  ((f32x4*)outp)[i] = v;
}

extern "C" void kernel_launch(void* const* d_in, const int* in_sizes, int n_in,
                              void* d_out, int out_size, void* d_ws, size_t ws_size,
                              hipStream_t stream) {
  const float* x = (const float*)d_in[0];
  const float* w_off = (const float*)d_in[1];
  const float* b_off = (const float*)d_in[2];
  const float* w_dcn = (const float*)d_in[3];
  const float* gamma = (const float*)d_in[4];
  const float* beta = (const float*)d_in[5];
  float* out = (float*)d_out;
  char* ws = (char*)d_ws;

  // ws layout: wT bf16 [0, 294912); wT2 bf16 [294912, 368640);
  //            xT bf16 NHWC [368640, 17145856); stats [17145856, 17146880);
  //            sc [17146880, 17147904)  -- total ~16.4 MB
  unsigned short* wT = (unsigned short*)(ws);
  unsigned short* wT2 = (unsigned short*)(ws + 294912);
  unsigned short* xT = (unsigned short*)(ws + 368640);
  float* stats = (float*)(ws + 17145856);
  float* sc = (float*)(ws + 17146880);

  hipMemsetAsync(stats, 0, 1024, stream);
  k_wprep<<<576, 256, 0, stream>>>(w_dcn, wT);
  k_wprep2<<<144, 256, 0, stream>>>(w_off, wT2);
  k_xpose<<<1024, 256, 0, stream>>>(x, xT);
  k_main<<<1024, 256, 0, stream>>>(xT, wT, wT2, b_off, out, stats);
  k_stats<<<1, 128, 0, stream>>>(stats, gamma, beta, sc);
  k_bn<<<8192, 256, 0, stream>>>(out, sc);
}